// Round 2
// baseline (153.536 us; speedup 1.0000x reference)
//
#include <hip/hip_runtime.h>

#define N_NODES 10000
#define E_EDGES 640000
#define C 128
#define PAD 10064          // replica stride in floats (non-pow2-multiple to spread channels)
#define NREP 8             // one replica per XCD
#define GB 128             // greduce blocks

// Per-XCD-local atomic: workgroup scope => no sc1 => RMW executes in the local
// XCD's L2 (fast, no fabric round-trip). Safe ONLY because each replica is
// touched by exactly one XCD (indexed by hardware XCC_ID).
__device__ __forceinline__ void atomic_add_l2(float* p, float v) {
    __hip_atomic_fetch_add(p, v, __ATOMIC_RELAXED, __HIP_MEMORY_SCOPE_WORKGROUP);
}
__device__ __forceinline__ void atomic_add_dev(float* p, float v) {
    __hip_atomic_fetch_add(p, v, __ATOMIC_RELAXED, __HIP_MEMORY_SCOPE_AGENT);
}
__device__ __forceinline__ int xcc_id() {
    unsigned x;
    asm volatile("s_getreg_b32 %0, hwreg(HW_REG_XCC_ID)" : "=s"(x));
    return (int)(x & 7);
}

template <bool XCD>
__global__ void k_deg(const int* __restrict__ col, const float* __restrict__ w,
                      float* __restrict__ degr) {
    float* my = degr + (XCD ? (size_t)xcc_id() * PAD : 0);
    int e = blockIdx.x * blockDim.x + threadIdx.x;
    if (e < E_EDGES) {
        if (XCD) atomic_add_l2(&my[col[e]], w[e]);
        else     atomic_add_dev(&my[col[e]], w[e]);
    }
}

// dinv[i] = rsqrt(1 + sum_r degr[r][i]); block 0 also computes s1 = colsum(W1)
__global__ void k_dinv(const float* __restrict__ degr, float* __restrict__ dinv, int R,
                       const float* __restrict__ W1, float* __restrict__ s1) {
    int i = blockIdx.x * blockDim.x + threadIdx.x;
    if (i < N_NODES) {
        float d = 1.0f;                       // self-loop weight
        for (int r = 0; r < R; ++r) d += degr[(size_t)r * PAD + i];
        dinv[i] = rsqrtf(d);
    }
    if (blockIdx.x == 0 && threadIdx.x < C) {
        int j = threadIdx.x;
        float s = 0.0f;
        for (int k = 0; k < C; ++k) s += W1[k * C + j];
        s1[j] = s;
    }
}

template <bool XCD>
__global__ void k_scatter(const int* __restrict__ row, const int* __restrict__ col,
                          const float* __restrict__ w, const float* __restrict__ dinv,
                          float* __restrict__ tar, float* __restrict__ tbr) {
    size_t off = XCD ? (size_t)xcc_id() * PAD : 0;
    float* ta = tar + off;
    float* tb = tbr + off;
    int e = blockIdx.x * blockDim.x + threadIdx.x;
    if (e < E_EDGES) {
        int r = row[e], c = col[e];
        float we = w[e];
        if (XCD) {
            atomic_add_l2(&ta[c], we * dinv[r]);
            atomic_add_l2(&tb[r], we * dinv[c]);
        } else {
            atomic_add_dev(&ta[c], we * dinv[r]);
            atomic_add_dev(&tb[r], we * dinv[c]);
        }
    }
}

// gpart[b][j] = sum_{i in block b's range} beta[i] * relu(alpha[i]*s1[j] + b1[j])
// alpha[i] = dinv[i]*ta[i] + dinv[i]^2 ; beta[i] = dinv[i]*tb[i] + dinv[i]^2
__global__ void k_greduce(const float* __restrict__ dinv, const float* __restrict__ tar,
                          const float* __restrict__ tbr, const float* __restrict__ s1,
                          const float* __restrict__ b1, float* __restrict__ gpart, int R) {
    int j = threadIdx.x;                          // channel 0..127
    float s1j = s1[j], b1j = b1[j];
    int per = (N_NODES + gridDim.x - 1) / gridDim.x;
    int i0 = blockIdx.x * per;
    int i1 = min(i0 + per, N_NODES);
    float acc = 0.0f;
    for (int i = i0; i < i1; ++i) {
        float di = dinv[i];                       // wave-uniform loads
        float ta = 0.0f, tb = 0.0f;
        for (int r = 0; r < R; ++r) {
            ta += tar[(size_t)r * PAD + i];
            tb += tbr[(size_t)r * PAD + i];
        }
        float self  = di * di;
        float alpha = fmaf(di, ta, self);
        float beta  = fmaf(di, tb, self);
        float h     = fmaf(alpha, s1j, b1j);
        acc += beta * fmaxf(h, 0.0f);             // exact relu
    }
    gpart[blockIdx.x * C + j] = acc;
}

// out[j] = (1/N) * sum_k G[k]*W2[k,j] + b2[j],  G[k] = sum_b gpart[b][k]
__global__ void k_final(const float* __restrict__ gpart, const float* __restrict__ W2,
                        const float* __restrict__ b2, float* __restrict__ out) {
    int j = threadIdx.x;
    __shared__ float Gs[C];
    float G = 0.0f;
    for (int b = 0; b < GB; ++b) G += gpart[b * C + j];   // coalesced
    Gs[j] = G;
    __syncthreads();
    float acc = 0.0f;
    for (int k = 0; k < C; ++k) acc += Gs[k] * W2[k * C + j];
    out[j] = acc * (1.0f / (float)N_NODES) + b2[j];
}

extern "C" void kernel_launch(void* const* d_in, const int* in_sizes, int n_in,
                              void* d_out, int out_size, void* d_ws, size_t ws_size,
                              hipStream_t stream) {
    const int*   eidx = (const int*)d_in[1];
    const int*   row  = eidx;             // edge_index[0]
    const int*   col  = eidx + E_EDGES;   // edge_index[1]
    const float* w    = (const float*)d_in[2];
    const float* W1   = (const float*)d_in[3];
    const float* b1   = (const float*)d_in[4];
    const float* W2   = (const float*)d_in[5];
    const float* b2   = (const float*)d_in[6];
    float* out = (float*)d_out;
    float* ws  = (float*)d_ws;

    size_t floats = ws_size / sizeof(float);
    size_t needR8 = (size_t)3 * NREP * PAD + N_NODES + C + (size_t)GB * C;
    const bool xcd = floats >= needR8;        // constant across calls -> deterministic
    const int  R   = xcd ? NREP : 1;

    float* degr  = ws;
    float* tar   = degr + (size_t)R * PAD;
    float* tbr   = tar  + (size_t)R * PAD;
    float* dinv  = tbr  + (size_t)R * PAD;
    float* s1    = dinv + N_NODES;
    float* gpart = s1 + C;

    const int edgeBlocks = (E_EDGES + 255) / 256;
    const int nodeBlocks = (N_NODES + 255) / 256;

    hipMemsetAsync(d_ws, 0, (size_t)3 * R * PAD * sizeof(float), stream);
    if (xcd) {
        k_deg<true>    <<<edgeBlocks, 256, 0, stream>>>(col, w, degr);
        k_dinv         <<<nodeBlocks, 256, 0, stream>>>(degr, dinv, R, W1, s1);
        k_scatter<true><<<edgeBlocks, 256, 0, stream>>>(row, col, w, dinv, tar, tbr);
    } else {
        k_deg<false>    <<<edgeBlocks, 256, 0, stream>>>(col, w, degr);
        k_dinv          <<<nodeBlocks, 256, 0, stream>>>(degr, dinv, R, W1, s1);
        k_scatter<false><<<edgeBlocks, 256, 0, stream>>>(row, col, w, dinv, tar, tbr);
    }
    k_greduce<<<GB, C, 0, stream>>>(dinv, tar, tbr, s1, b1, gpart, R);
    k_final  <<<1, C, 0, stream>>>(gpart, W2, b2, out);
}

// Round 3
// 116.613 us; speedup vs baseline: 1.3166x; 1.3166x over previous
//
#include <hip/hip_runtime.h>

#define N_NODES 10000
#define E_EDGES 640000
#define C 128
#define NB_MAX 128           // max partial-replica blocks for deg/scatter
#define GB 125               // greduce blocks
#define GCHUNK 80            // nodes per greduce block (125*80 = 10000)

// ---------------- deg: LDS-privatized scatter of edge weights by col ----------------
__global__ __launch_bounds__(512) void k_deg(const int* __restrict__ col,
                                             const float* __restrict__ w,
                                             float* __restrict__ degp, int nb) {
    __shared__ float sdeg[N_NODES];                       // 40 KB
    for (int i = threadIdx.x; i < N_NODES; i += blockDim.x) sdeg[i] = 0.0f;
    __syncthreads();
    int chunk = (E_EDGES + nb - 1) / nb;
    int e0 = blockIdx.x * chunk;
    int e1 = min(e0 + chunk, E_EDGES);
    for (int e = e0 + (int)threadIdx.x; e < e1; e += blockDim.x)
        atomicAdd(&sdeg[col[e]], w[e]);                   // ds_add_f32, LDS-side
    __syncthreads();
    float* out = degp + (size_t)blockIdx.x * N_NODES;
    for (int i = threadIdx.x; i < N_NODES; i += blockDim.x) out[i] = sdeg[i];
}

// ---------------- dinv[i] = rsqrt(1 + sum_b degp[b][i]); block 0: s1 = colsum(W1) ----
__global__ void k_dinv(const float* __restrict__ degp, float* __restrict__ dinv, int nb,
                       const float* __restrict__ W1, float* __restrict__ s1) {
    int i = blockIdx.x * blockDim.x + threadIdx.x;
    if (i < N_NODES) {
        float d = 1.0f;                                   // self-loop
        for (int b = 0; b < nb; ++b) d += degp[(size_t)b * N_NODES + i];  // coalesced
        dinv[i] = rsqrtf(d);
    }
    if (blockIdx.x == 0 && threadIdx.x < C) {
        int j = threadIdx.x;
        float s = 0.0f;
        for (int k = 0; k < C; ++k) s += W1[k * C + j];   // coalesced across j
        s1[j] = s;
    }
}

// ---------------- scatter: LDS-privatized t_a (by col) and t_b (by row) -------------
__global__ __launch_bounds__(512) void k_scatter(const int* __restrict__ row,
                                                 const int* __restrict__ col,
                                                 const float* __restrict__ w,
                                                 const float* __restrict__ dinv,
                                                 float* __restrict__ tap,
                                                 float* __restrict__ tbp, int nb) {
    __shared__ float sta[N_NODES];                        // 40 KB
    __shared__ float stb[N_NODES];                        // 40 KB  (80 KB total, 2 blk/CU)
    for (int i = threadIdx.x; i < N_NODES; i += blockDim.x) { sta[i] = 0.0f; stb[i] = 0.0f; }
    __syncthreads();
    int chunk = (E_EDGES + nb - 1) / nb;
    int e0 = blockIdx.x * chunk;
    int e1 = min(e0 + chunk, E_EDGES);
    for (int e = e0 + (int)threadIdx.x; e < e1; e += blockDim.x) {
        int r = row[e], c = col[e];
        float we = w[e];
        atomicAdd(&sta[c], we * dinv[r]);                 // LDS atomics only
        atomicAdd(&stb[r], we * dinv[c]);
    }
    __syncthreads();
    float* oa = tap + (size_t)blockIdx.x * N_NODES;
    float* ob = tbp + (size_t)blockIdx.x * N_NODES;
    for (int i = threadIdx.x; i < N_NODES; i += blockDim.x) {  // coalesced flush
        oa[i] = sta[i];
        ob[i] = stb[i];
    }
}

// ---------------- fold partials -> alpha/beta in LDS, then channel reduction --------
// gpart[blk][j] = sum_{i in chunk} beta[i] * relu(alpha[i]*s1[j] + b1[j])
__global__ __launch_bounds__(C) void k_greduce(const float* __restrict__ tap,
                                               const float* __restrict__ tbp,
                                               const float* __restrict__ dinv,
                                               const float* __restrict__ s1,
                                               const float* __restrict__ b1,
                                               float* __restrict__ gpart, int nb) {
    __shared__ float salpha[GCHUNK];
    __shared__ float sbeta[GCHUNK];
    int i0 = blockIdx.x * GCHUNK;
    int n = min(GCHUNK, N_NODES - i0);
    for (int t = threadIdx.x; t < n; t += blockDim.x) {   // lanes -> consecutive nodes
        int i = i0 + t;
        float ta = 0.0f, tb = 0.0f;
        for (int b = 0; b < nb; ++b) {                    // coalesced across lanes
            ta += tap[(size_t)b * N_NODES + i];
            tb += tbp[(size_t)b * N_NODES + i];
        }
        float di = dinv[i], self = di * di;
        salpha[t] = fmaf(di, ta, self);
        sbeta[t]  = fmaf(di, tb, self);
    }
    __syncthreads();
    int j = threadIdx.x;                                  // channel
    float s1j = s1[j], b1j = b1[j], acc = 0.0f;
    for (int t = 0; t < n; ++t) {                         // LDS broadcast reads
        float h = fmaf(salpha[t], s1j, b1j);
        acc += sbeta[t] * fmaxf(h, 0.0f);                 // exact relu
    }
    gpart[blockIdx.x * C + j] = acc;
}

// ---------------- out[j] = (1/N) * sum_k G[k]*W2[k,j] + b2[j] -----------------------
__global__ __launch_bounds__(C) void k_final(const float* __restrict__ gpart,
                                             const float* __restrict__ W2,
                                             const float* __restrict__ b2,
                                             float* __restrict__ out) {
    int j = threadIdx.x;
    __shared__ float Gs[C];
    float G = 0.0f;
    for (int b = 0; b < GB; ++b) G += gpart[b * C + j];   // coalesced
    Gs[j] = G;
    __syncthreads();
    float acc = 0.0f;
    for (int k = 0; k < C; ++k) acc += Gs[k] * W2[k * C + j];
    out[j] = acc * (1.0f / (float)N_NODES) + b2[j];
}

extern "C" void kernel_launch(void* const* d_in, const int* in_sizes, int n_in,
                              void* d_out, int out_size, void* d_ws, size_t ws_size,
                              hipStream_t stream) {
    const int*   eidx = (const int*)d_in[1];
    const int*   row  = eidx;             // edge_index[0]
    const int*   col  = eidx + E_EDGES;   // edge_index[1]
    const float* w    = (const float*)d_in[2];
    const float* W1   = (const float*)d_in[3];
    const float* b1   = (const float*)d_in[4];
    const float* W2   = (const float*)d_in[5];
    const float* b2   = (const float*)d_in[6];
    float* out = (float*)d_out;
    float* ws  = (float*)d_ws;

    // Size the partial-replica count to the workspace. degp aliases tap (their
    // live ranges don't overlap: degp is dead after k_dinv, tap written after).
    size_t floats = ws_size / sizeof(float);
    size_t fixed  = N_NODES + C + (size_t)GB * C;         // dinv + s1 + gpart
    int nb = 1;
    if (floats > fixed + 2u * N_NODES) {
        size_t m = (floats - fixed) / (2u * N_NODES);     // replicas of (tap,tbp)
        nb = (int)(m < NB_MAX ? m : NB_MAX);
        if (nb < 1) nb = 1;
    }

    float* tap   = ws;                                    // nb * N   (also degp)
    float* degp  = tap;
    float* tbp   = tap + (size_t)nb * N_NODES;            // nb * N
    float* dinv  = tbp + (size_t)nb * N_NODES;
    float* s1    = dinv + N_NODES;
    float* gpart = s1 + C;

    const int nodeBlocks = (N_NODES + 255) / 256;

    k_deg    <<<nb, 512, 0, stream>>>(col, w, degp, nb);
    k_dinv   <<<nodeBlocks, 256, 0, stream>>>(degp, dinv, nb, W1, s1);
    k_scatter<<<nb, 512, 0, stream>>>(row, col, w, dinv, tap, tbp, nb);
    k_greduce<<<GB, C, 0, stream>>>(tap, tbp, dinv, s1, b1, gpart, nb);
    k_final  <<<1, C, 0, stream>>>(gpart, W2, b2, out);
}

// Round 4
// 78.824 us; speedup vs baseline: 1.9478x; 1.4794x over previous
//
#include <hip/hip_runtime.h>

#define N_NODES 10000
#define E_EDGES 640000
#define C 128
#define NB_MAX 128           // partial-replica blocks for deg/scatter
#define GCHUNK 128           // nodes per greduce block
#define GB 79                // ceil(10000/128)

// ---------------- deg: LDS-privatized scatter of edge weights by col ----------------
__global__ __launch_bounds__(512) void k_deg(const int* __restrict__ col,
                                             const float* __restrict__ w,
                                             float* __restrict__ degp, int nb) {
    __shared__ float sdeg[N_NODES];                       // 40 KB
    for (int i = threadIdx.x; i < N_NODES; i += blockDim.x) sdeg[i] = 0.0f;
    __syncthreads();
    int chunk = (E_EDGES + nb - 1) / nb;
    int e0 = blockIdx.x * chunk;
    int e1 = min(e0 + chunk, E_EDGES);
    for (int e = e0 + (int)threadIdx.x; e < e1; e += blockDim.x)
        atomicAdd(&sdeg[col[e]], w[e]);                   // ds_add_f32, LDS-side
    __syncthreads();
    float* out = degp + (size_t)blockIdx.x * N_NODES;
    for (int i = threadIdx.x; i < N_NODES; i += blockDim.x) out[i] = sdeg[i];
}

// ---------------- dinv[i] = rsqrt(1 + sum_b degp[b][i]); block 0: s1 = colsum(W1) ----
template <int NB>
__global__ void k_dinv(const float* __restrict__ degp, float* __restrict__ dinv, int nbRt,
                       const float* __restrict__ W1, float* __restrict__ s1) {
    const int nb = NB ? NB : nbRt;
    int i = blockIdx.x * blockDim.x + threadIdx.x;
    if (i < N_NODES) {
        float d = 1.0f;                                   // self-loop
        #pragma unroll 16
        for (int b = 0; b < nb; ++b) d += degp[(size_t)b * N_NODES + i];  // coalesced, batched
        dinv[i] = rsqrtf(d);
    }
    if (blockIdx.x == 0 && threadIdx.x < C) {
        int j = threadIdx.x;
        float s = 0.0f;
        #pragma unroll 16
        for (int k = 0; k < C; ++k) s += W1[k * C + j];   // coalesced across j
        s1[j] = s;
    }
}

// ---------------- scatter: LDS-privatized t_a (by col) and t_b (by row) -------------
__global__ __launch_bounds__(512) void k_scatter(const int* __restrict__ row,
                                                 const int* __restrict__ col,
                                                 const float* __restrict__ w,
                                                 const float* __restrict__ dinv,
                                                 float* __restrict__ tap,
                                                 float* __restrict__ tbp, int nb) {
    __shared__ float sta[N_NODES];                        // 40 KB
    __shared__ float stb[N_NODES];                        // 40 KB  (80 KB total, 2 blk/CU)
    for (int i = threadIdx.x; i < N_NODES; i += blockDim.x) { sta[i] = 0.0f; stb[i] = 0.0f; }
    __syncthreads();
    int chunk = (E_EDGES + nb - 1) / nb;
    int e0 = blockIdx.x * chunk;
    int e1 = min(e0 + chunk, E_EDGES);
    for (int e = e0 + (int)threadIdx.x; e < e1; e += blockDim.x) {
        int r = row[e], c = col[e];
        float we = w[e];
        atomicAdd(&sta[c], we * dinv[r]);                 // LDS atomics only
        atomicAdd(&stb[r], we * dinv[c]);
    }
    __syncthreads();
    float* oa = tap + (size_t)blockIdx.x * N_NODES;
    float* ob = tbp + (size_t)blockIdx.x * N_NODES;
    for (int i = threadIdx.x; i < N_NODES; i += blockDim.x) {  // coalesced flush
        oa[i] = sta[i];
        ob[i] = stb[i];
    }
}

// ---------------- fold partials -> alpha/beta in LDS, then channel reduction --------
// gpart[blk][j] = sum_{i in chunk} beta[i] * relu(alpha[i]*s1[j] + b1[j])
template <int NB>
__global__ __launch_bounds__(C) void k_greduce(const float* __restrict__ tap,
                                               const float* __restrict__ tbp,
                                               const float* __restrict__ dinv,
                                               const float* __restrict__ s1,
                                               const float* __restrict__ b1,
                                               float* __restrict__ gpart, int nbRt) {
    const int nb = NB ? NB : nbRt;
    __shared__ float salpha[GCHUNK];
    __shared__ float sbeta[GCHUNK];
    int i0 = blockIdx.x * GCHUNK;
    int n = min(GCHUNK, N_NODES - i0);
    int t = threadIdx.x;                                  // one node per thread
    if (t < n) {
        int i = i0 + t;
        float ta = 0.0f, tb = 0.0f;
        #pragma unroll 16
        for (int b = 0; b < nb; ++b) {                    // coalesced, batched loads
            ta += tap[(size_t)b * N_NODES + i];
            tb += tbp[(size_t)b * N_NODES + i];
        }
        float di = dinv[i], self = di * di;
        salpha[t] = fmaf(di, ta, self);
        sbeta[t]  = fmaf(di, tb, self);
    }
    __syncthreads();
    int j = threadIdx.x;                                  // channel
    float s1j = s1[j], b1j = b1[j], acc = 0.0f;
    for (int tt = 0; tt < n; ++tt) {                      // LDS broadcast reads
        float h = fmaf(salpha[tt], s1j, b1j);
        acc += sbeta[tt] * fmaxf(h, 0.0f);                // exact relu
    }
    gpart[blockIdx.x * C + j] = acc;
}

// ---------------- out[j] = (1/N) * sum_k G[k]*W2[k,j] + b2[j] -----------------------
__global__ __launch_bounds__(C) void k_final(const float* __restrict__ gpart,
                                             const float* __restrict__ W2,
                                             const float* __restrict__ b2,
                                             float* __restrict__ out) {
    int j = threadIdx.x;
    __shared__ float Gs[C];
    float G = 0.0f;
    #pragma unroll 8
    for (int b = 0; b < GB; ++b) G += gpart[b * C + j];   // coalesced
    Gs[j] = G;
    __syncthreads();
    float acc = 0.0f;
    #pragma unroll 16
    for (int k = 0; k < C; ++k) acc += Gs[k] * W2[k * C + j];
    out[j] = acc * (1.0f / (float)N_NODES) + b2[j];
}

extern "C" void kernel_launch(void* const* d_in, const int* in_sizes, int n_in,
                              void* d_out, int out_size, void* d_ws, size_t ws_size,
                              hipStream_t stream) {
    const int*   eidx = (const int*)d_in[1];
    const int*   row  = eidx;             // edge_index[0]
    const int*   col  = eidx + E_EDGES;   // edge_index[1]
    const float* w    = (const float*)d_in[2];
    const float* W1   = (const float*)d_in[3];
    const float* b1   = (const float*)d_in[4];
    const float* W2   = (const float*)d_in[5];
    const float* b2   = (const float*)d_in[6];
    float* out = (float*)d_out;
    float* ws  = (float*)d_ws;

    // Size the partial-replica count to the workspace. degp aliases tap (their
    // live ranges don't overlap: degp is dead after k_dinv, tap written after).
    size_t floats = ws_size / sizeof(float);
    size_t fixed  = N_NODES + C + (size_t)GB * C;         // dinv + s1 + gpart
    int nb = 1;
    if (floats > fixed + 2u * N_NODES) {
        size_t m = (floats - fixed) / (2u * N_NODES);     // replicas of (tap,tbp)
        nb = (int)(m < NB_MAX ? m : NB_MAX);
        if (nb < 1) nb = 1;
    }

    float* tap   = ws;                                    // nb * N   (also degp)
    float* degp  = tap;
    float* tbp   = tap + (size_t)nb * N_NODES;            // nb * N
    float* dinv  = tbp + (size_t)nb * N_NODES;
    float* s1    = dinv + N_NODES;
    float* gpart = s1 + C;

    const int nodeBlocks = (N_NODES + 255) / 256;

    k_deg    <<<nb, 512, 0, stream>>>(col, w, degp, nb);
    if (nb == NB_MAX) {
        k_dinv<NB_MAX>   <<<nodeBlocks, 256, 0, stream>>>(degp, dinv, nb, W1, s1);
        k_scatter        <<<nb, 512, 0, stream>>>(row, col, w, dinv, tap, tbp, nb);
        k_greduce<NB_MAX><<<GB, C, 0, stream>>>(tap, tbp, dinv, s1, b1, gpart, nb);
    } else {
        k_dinv<0>    <<<nodeBlocks, 256, 0, stream>>>(degp, dinv, nb, W1, s1);
        k_scatter    <<<nb, 512, 0, stream>>>(row, col, w, dinv, tap, tbp, nb);
        k_greduce<0> <<<GB, C, 0, stream>>>(tap, tbp, dinv, s1, b1, gpart, nb);
    }
    k_final  <<<1, C, 0, stream>>>(gpart, W2, b2, out);
}